// Round 1
// 13263.693 us; speedup vs baseline: 1.7251x; 1.7251x over previous
//
#include <hip/hip_runtime.h>
#include <math.h>

#define D_MODEL 768
#define N_HEAD 12
#define D_HEAD 64
#define D_INNER 3072
#define N_LAYER 12
#define MEM_LEN 512
#define BSZ 4
#define QLEN 1024
#define KLEN (MEM_LEN + QLEN)   // 1536
#define SCALE_ATTN 0.125f
#define EMB_SCALE 27.712812921102035f

typedef __bf16 bf16x8 __attribute__((ext_vector_type(8)));
typedef float f32x4 __attribute__((ext_vector_type(4)));

// split-bf16: x ~= hi + lo, hi = bf16(x), lo = bf16(x - hi). A@B ~= Ah@Bh + Ah@Bl + Al@Bh
// (dropped Al@Bl term ~2^-18 relative -> keeps absmax at fp32-noise level).

__device__ __forceinline__ void gl_lds16(const void* g, void* l) {
    __builtin_amdgcn_global_load_lds((const __attribute__((address_space(1))) unsigned int*)g,
                                     (__attribute__((address_space(3))) unsigned int*)l,
                                     16, 0, 0);
}

// ---------------------------------------------------------------- small kernels

// sinusoidal relative position embedding (split bf16), pos_seq = klen-1 .. 0
__global__ __launch_bounds__(256) void pos_emb_kernel(__bf16* __restrict__ ph,
                                                      __bf16* __restrict__ pl) {
    int j = blockIdx.x;
    float pos = (float)(KLEN - 1 - j);
    for (int e = 0; e < 3; e++) {
        int d = e * 256 + threadIdx.x;
        int tt = (d < 384) ? d : d - 384;
        float freq = expf(-9.210340371976184f * ((float)(2 * tt) * (1.0f / 768.0f)));
        float arg = pos * freq;
        float v = (d < 384) ? sinf(arg) : cosf(arg);
        __bf16 h = (__bf16)v;
        ph[(size_t)j * 768 + d] = h;
        pl[(size_t)j * 768 + d] = (__bf16)(v - (float)h);
    }
}

__global__ __launch_bounds__(256) void embed_kernel(const int* __restrict__ ids,
                                                    const float* __restrict__ emb,
                                                    float* __restrict__ core) {
    int qb = blockIdx.x;
    int q = qb >> 2, b = qb & 3;
    int id = ids[b * QLEN + q];
    const float* e = emb + (size_t)id * 768;
    float* o = core + (size_t)qb * 768;
    for (int k = threadIdx.x; k < 768; k += 256) o[k] = e[k] * EMB_SCALE;
}

// cat = [mems[l]; core] as split bf16 ([KLEN*B, D]); also writes new_mems (fp32 exact copy)
__global__ __launch_bounds__(256) void prep_kernel(const float* __restrict__ core,
                                                   const float* __restrict__ mems,
                                                   __bf16* __restrict__ ch,
                                                   __bf16* __restrict__ cl,
                                                   float* __restrict__ omems,
                                                   int layer) {
    int jb = blockIdx.x;
    int j = jb >> 2, b = jb & 3;
    for (int e = 0; e < 3; e++) {
        int d = e * 256 + threadIdx.x;
        float v;
        if (j < MEM_LEN)
            v = mems[(((size_t)layer * MEM_LEN + j) * 4 + b) * 768 + d];
        else
            v = core[((size_t)(j - MEM_LEN) * 4 + b) * 768 + d];
        __bf16 h = (__bf16)v;
        ch[(size_t)jb * 768 + d] = h;
        cl[(size_t)jb * 768 + d] = (__bf16)(v - (float)h);
        if (j >= QLEN)
            omems[(((size_t)layer * MEM_LEN + (j - QLEN)) * 4 + b) * 768 + d] = v;
    }
}

// weight transpose + split: W fp32 [K][N] -> Th,Tl bf16 [N][K]
__global__ __launch_bounds__(256) void wconvT_kernel(const float* __restrict__ W,
                                                     __bf16* __restrict__ Th,
                                                     __bf16* __restrict__ Tl,
                                                     int K, int N) {
    __shared__ float s[64][65];
    int n0 = blockIdx.x * 64, k0 = blockIdx.y * 64;
    int t = threadIdx.x;
    int c = t & 63, r0 = (t >> 6) * 16;
#pragma unroll 4
    for (int i = 0; i < 16; i++)
        s[r0 + i][c] = W[(size_t)(k0 + r0 + i) * N + n0 + c];
    __syncthreads();
    int n = t >> 2, kc = (t & 3) * 16;
    size_t base = (size_t)(n0 + n) * K + k0 + kc;
#pragma unroll 4
    for (int i = 0; i < 16; i++) {
        float v = s[kc + i][n];
        __bf16 h = (__bf16)v;
        Th[base + i] = h;
        Tl[base + i] = (__bf16)(v - (float)h);
    }
}

// ---------------------------------------------------------------- MFMA GEMM
// C[M,N] = (Ah+Al)[M,K] @ (Bh+Bl)^T stored [N,K]   (3-term split-bf16)
// 128x128 tile, BK=32, 4 waves (2x2), each wave 64x64 via 4x4 frags of 16x16x32.
// FLAGS: 1 bias, 2 relu, 4 residual, 8 write split-bf16 out (else fp32 out)
template <int FLAGS>
__global__ __launch_bounds__(256) void mfma_gemm(
        const __bf16* __restrict__ Ah, const __bf16* __restrict__ Al,
        const __bf16* __restrict__ Bh, const __bf16* __restrict__ Bl,
        const float* __restrict__ bias, const float* __restrict__ res,
        float* __restrict__ C, __bf16* __restrict__ Ch, __bf16* __restrict__ Cl,
        int M, int N, int K) {
    __shared__ __attribute__((aligned(16))) __bf16 sAh[128][32];
    __shared__ __attribute__((aligned(16))) __bf16 sAl[128][32];
    __shared__ __attribute__((aligned(16))) __bf16 sBh[128][32];
    __shared__ __attribute__((aligned(16))) __bf16 sBl[128][32];
    const int t = threadIdx.x;
    const int lane = t & 63;
    const int w = t >> 6;
    const int lr = lane & 15, lg = lane >> 4;     // frag row/col, k-group
    const int wr = w >> 1, wc = w & 1;            // wave 2x2 grid
    const int m0 = blockIdx.y * 128, n0 = blockIdx.x * 128;
    const int srow = lane >> 2;                   // staging: row within 16-row chunk
    const int skc = (lane & 3) * 8;               // staging: k elem offset

    f32x4 acc[4][4] = {};

    for (int k0 = 0; k0 < K; k0 += 32) {
#pragma unroll
        for (int e = 0; e < 2; e++) {
            int c = w * 2 + e;                    // chunk 0..7 (16 rows each)
            int gr = c * 16 + srow;
            size_t aoff = (size_t)(m0 + gr) * K + k0 + skc;
            size_t boff = (size_t)(n0 + gr) * K + k0 + skc;
            gl_lds16(Ah + aoff, &sAh[c * 16][0]);
            gl_lds16(Al + aoff, &sAl[c * 16][0]);
            gl_lds16(Bh + boff, &sBh[c * 16][0]);
            gl_lds16(Bl + boff, &sBl[c * 16][0]);
        }
        __syncthreads();   // drains vmcnt (gload_lds) before any wave proceeds
        bf16x8 a_h[4], a_l[4];
#pragma unroll
        for (int mi = 0; mi < 4; mi++) {
            int r = wr * 64 + mi * 16 + lr;
            a_h[mi] = *(const bf16x8*)&sAh[r][lg * 8];
            a_l[mi] = *(const bf16x8*)&sAl[r][lg * 8];
        }
#pragma unroll
        for (int nj = 0; nj < 4; nj++) {
            int cn = wc * 64 + nj * 16 + lr;
            bf16x8 b_h = *(const bf16x8*)&sBh[cn][lg * 8];
            bf16x8 b_l = *(const bf16x8*)&sBl[cn][lg * 8];
#pragma unroll
            for (int mi = 0; mi < 4; mi++) {
                acc[mi][nj] = __builtin_amdgcn_mfma_f32_16x16x32_bf16(a_h[mi], b_h, acc[mi][nj], 0, 0, 0);
                acc[mi][nj] = __builtin_amdgcn_mfma_f32_16x16x32_bf16(a_h[mi], b_l, acc[mi][nj], 0, 0, 0);
                acc[mi][nj] = __builtin_amdgcn_mfma_f32_16x16x32_bf16(a_l[mi], b_h, acc[mi][nj], 0, 0, 0);
            }
        }
        __syncthreads();   // all reads done before next stage overwrites
    }
    // epilogue: D col = lane&15, row = 4*(lane>>4)+reg (m89-verified layout)
#pragma unroll
    for (int mi = 0; mi < 4; mi++)
#pragma unroll
        for (int nj = 0; nj < 4; nj++) {
            int col = n0 + wc * 64 + nj * 16 + lr;
            float bv = (FLAGS & 1) ? bias[col] : 0.f;
#pragma unroll
            for (int r = 0; r < 4; r++) {
                int row = m0 + wr * 64 + mi * 16 + lg * 4 + r;
                float v = acc[mi][nj][r] + bv;
                if (FLAGS & 4) v += res[(size_t)row * N + col];
                if (FLAGS & 2) v = fmaxf(v, 0.f);
                if (FLAGS & 8) {
                    __bf16 h = (__bf16)v;
                    Ch[(size_t)row * N + col] = h;
                    Cl[(size_t)row * N + col] = (__bf16)(v - (float)h);
                } else {
                    C[(size_t)row * N + col] = v;
                }
            }
        }
}

// ---------------------------------------------------------------- flash attention (unchanged
// except epilogue writes split-bf16 so the o-proj MFMA GEMM consumes it directly)
__global__ __launch_bounds__(256) void attn_flash_kernel(const float* __restrict__ wh,
                                                         const float* __restrict__ rh,
                                                         const float* __restrict__ rwb,
                                                         const float* __restrict__ rrb,
                                                         __bf16* __restrict__ aout_h,
                                                         __bf16* __restrict__ aout_l) {
    __shared__ float Qw[64][65];
    __shared__ float db_s[64];
    __shared__ float buf[8256];
    float (*Ks)[65] = (float (*)[65])buf;
    float (*Rs)[65] = (float (*)[65])buf;
    float (*Vs)[64] = (float (*)[64])buf;
    float (*Ps)[65] = (float (*)[65])(buf + 4096);

    int qt = blockIdx.x;
    int i0 = qt * 64;
    int b = blockIdx.y / N_HEAD;
    int n = blockIdx.y % N_HEAD;
    int t = threadIdx.x;
    int tx = t & 15, ty = t >> 4;

#pragma unroll
    for (int rep = 0; rep < 4; rep++) {
        int r = rep * 16 + (t >> 4);
        int c = (t & 15) * 4;
        float4 qv = *(const float4*)&wh[((size_t)(MEM_LEN + i0 + r) * 4 + b) * 2304 + n * 64 + c];
        float4 bw = *(const float4*)&rwb[n * 64 + c];
        Qw[r][c + 0] = qv.x + bw.x;
        Qw[r][c + 1] = qv.y + bw.y;
        Qw[r][c + 2] = qv.z + bw.z;
        Qw[r][c + 3] = qv.w + bw.w;
    }
    if (t < 64) db_s[t] = rrb[n * 64 + t] - rwb[n * 64 + t];

    float m_r[4], l_r[4], o_r[4][4];
#pragma unroll
    for (int y = 0; y < 4; y++) {
        m_r[y] = -1e30f; l_r[y] = 0.f;
#pragma unroll
        for (int x = 0; x < 4; x++) o_r[y][x] = 0.f;
    }

    int ntile = qt + 9;
    for (int jt = 0; jt < ntile; jt++) {
        int j0 = jt * 64;
        __syncthreads();
#pragma unroll
        for (int rep = 0; rep < 4; rep++) {
            int r = rep * 16 + (t >> 4);
            int c = (t & 15) * 4;
            float4 v = *(const float4*)&wh[((size_t)(j0 + r) * 4 + b) * 2304 + 768 + n * 64 + c];
            Ks[r][c + 0] = v.x; Ks[r][c + 1] = v.y; Ks[r][c + 2] = v.z; Ks[r][c + 3] = v.w;
        }
        __syncthreads();
        float p[4][4] = {};
        for (int kk = 0; kk < 64; kk++) {
            float av[4], bv[4];
#pragma unroll
            for (int y = 0; y < 4; y++) av[y] = Qw[ty * 4 + y][kk];
#pragma unroll
            for (int x = 0; x < 4; x++) bv[x] = Ks[tx * 4 + x][kk];
#pragma unroll
            for (int y = 0; y < 4; y++)
#pragma unroll
                for (int x = 0; x < 4; x++)
                    p[y][x] = fmaf(av[y], bv[x], p[y][x]);
        }
        __syncthreads();
        int rbase = j0 - i0 + 960;
        for (int s = (t >> 4); s < 127; s += 16) {
            int g = rbase + s; if (g > KLEN - 1) g = KLEN - 1;
            int c = (t & 15) * 4;
            float4 v = *(const float4*)&rh[(size_t)g * 768 + n * 64 + c];
            Rs[s][c + 0] = v.x; Rs[s][c + 1] = v.y; Rs[s][c + 2] = v.z; Rs[s][c + 3] = v.w;
        }
        __syncthreads();
        {
            int sb = 60 + 4 * (tx - ty);
            for (int kk = 0; kk < 64; kk++) {
                float dbk = db_s[kk];
                float av[4], r7[7];
#pragma unroll
                for (int y = 0; y < 4; y++) av[y] = Qw[ty * 4 + y][kk] + dbk;
#pragma unroll
                for (int u = 0; u < 7; u++) r7[u] = Rs[sb + u][kk];
#pragma unroll
                for (int y = 0; y < 4; y++)
#pragma unroll
                    for (int x = 0; x < 4; x++)
                        p[y][x] = fmaf(av[y], r7[3 + x - y], p[y][x]);
            }
        }
        float pm[4], rs[4];
#pragma unroll
        for (int y = 0; y < 4; y++) {
            int ig = i0 + ty * 4 + y;
            float mx = -1e30f;
#pragma unroll
            for (int x = 0; x < 4; x++) {
                int jg = j0 + tx * 4 + x;
                float sc = (jg - ig <= MEM_LEN) ? p[y][x] * SCALE_ATTN : -1e30f;
                p[y][x] = sc;
                mx = fmaxf(mx, sc);
            }
            pm[y] = mx;
        }
#pragma unroll
        for (int off = 1; off < 16; off <<= 1)
#pragma unroll
            for (int y = 0; y < 4; y++) pm[y] = fmaxf(pm[y], __shfl_xor(pm[y], off));
#pragma unroll
        for (int y = 0; y < 4; y++) {
            float nm = fmaxf(m_r[y], pm[y]);
            float al = __expf(m_r[y] - nm);
            m_r[y] = nm;
            float sum = 0.f;
#pragma unroll
            for (int x = 0; x < 4; x++) {
                float e = __expf(p[y][x] - nm);
                p[y][x] = e;
                sum += e;
            }
            rs[y] = sum;
            l_r[y] *= al;
#pragma unroll
            for (int x = 0; x < 4; x++) o_r[y][x] *= al;
        }
#pragma unroll
        for (int off = 1; off < 16; off <<= 1)
#pragma unroll
            for (int y = 0; y < 4; y++) rs[y] += __shfl_xor(rs[y], off);
#pragma unroll
        for (int y = 0; y < 4; y++) l_r[y] += rs[y];
        __syncthreads();
#pragma unroll
        for (int y = 0; y < 4; y++)
#pragma unroll
            for (int x = 0; x < 4; x++)
                Ps[tx * 4 + x][ty * 4 + y] = p[y][x];
#pragma unroll
        for (int rep = 0; rep < 4; rep++) {
            int r = rep * 16 + (t >> 4);
            int c = (t & 15) * 4;
            *(float4*)&Vs[r][c] =
                *(const float4*)&wh[((size_t)(j0 + r) * 4 + b) * 2304 + 1536 + n * 64 + c];
        }
        __syncthreads();
        for (int j = 0; j < 64; j++) {
            float a4[4], b4[4];
#pragma unroll
            for (int y = 0; y < 4; y++) a4[y] = Ps[j][ty * 4 + y];
#pragma unroll
            for (int x = 0; x < 4; x++) b4[x] = Vs[j][tx * 4 + x];
#pragma unroll
            for (int y = 0; y < 4; y++)
#pragma unroll
                for (int x = 0; x < 4; x++)
                    o_r[y][x] = fmaf(a4[y], b4[x], o_r[y][x]);
        }
    }
#pragma unroll
    for (int y = 0; y < 4; y++) {
        float inv = 1.0f / l_r[y];
        int ig = i0 + ty * 4 + y;
        size_t base = ((size_t)ig * 4 + b) * 768 + n * 64 + tx * 4;
#pragma unroll
        for (int x = 0; x < 4; x++) {
            float v = o_r[y][x] * inv;
            __bf16 h = (__bf16)v;
            aout_h[base + x] = h;
            aout_l[base + x] = (__bf16)(v - (float)h);
        }
    }
}

// LayerNorm; SPLIT=1 also writes split-bf16 copy (feeds the ff1 MFMA GEMM)
template <int SPLIT>
__global__ __launch_bounds__(256) void ln_kernel(const float* __restrict__ in,
                                                 const float* __restrict__ g,
                                                 const float* __restrict__ be,
                                                 float* __restrict__ out,
                                                 __bf16* __restrict__ oh,
                                                 __bf16* __restrict__ ol) {
    __shared__ float s1[256], s2[256];
    int row = blockIdx.x, t = threadIdx.x;
    const float* x = in + (size_t)row * 768;
    float v0 = x[t], v1 = x[t + 256], v2 = x[t + 512];
    s1[t] = v0 + v1 + v2;
    s2[t] = v0 * v0 + v1 * v1 + v2 * v2;
    __syncthreads();
    for (int s = 128; s > 0; s >>= 1) {
        if (t < s) { s1[t] += s1[t + s]; s2[t] += s2[t + s]; }
        __syncthreads();
    }
    float mean = s1[0] * (1.0f / 768.0f);
    float var = s2[0] * (1.0f / 768.0f) - mean * mean;
    float rs = rsqrtf(var + 1e-5f);
    float* o = out + (size_t)row * 768;
    float r0 = (v0 - mean) * rs * g[t]       + be[t];
    float r1 = (v1 - mean) * rs * g[t + 256] + be[t + 256];
    float r2 = (v2 - mean) * rs * g[t + 512] + be[t + 512];
    o[t] = r0; o[t + 256] = r1; o[t + 512] = r2;
    if (SPLIT) {
        size_t bo = (size_t)row * 768;
        __bf16 h0 = (__bf16)r0, h1 = (__bf16)r1, h2 = (__bf16)r2;
        oh[bo + t] = h0;       ol[bo + t]       = (__bf16)(r0 - (float)h0);
        oh[bo + t + 256] = h1; ol[bo + t + 256] = (__bf16)(r1 - (float)h1);
        oh[bo + t + 512] = h2; ol[bo + t + 512] = (__bf16)(r2 - (float)h2);
    }
}

__global__ __launch_bounds__(64) void logits_kernel(const float* __restrict__ core,
                                                    const float* __restrict__ qa_w,
                                                    const float* __restrict__ qa_b,
                                                    float* __restrict__ out) {
    int row = blockIdx.x;
    int q = row >> 2, b = row & 3;
    const float* x = core + (size_t)row * 768;
    float a0 = 0.f, a1 = 0.f;
    for (int d = threadIdx.x; d < 768; d += 64) {
        float xv = x[d];
        a0 = fmaf(xv, qa_w[2 * d], a0);
        a1 = fmaf(xv, qa_w[2 * d + 1], a1);
    }
    for (int off = 32; off > 0; off >>= 1) {
        a0 += __shfl_down(a0, off);
        a1 += __shfl_down(a1, off);
    }
    if (threadIdx.x == 0) {
        out[b * QLEN + q]        = a0 + qa_b[0];
        out[4096 + b * QLEN + q] = a1 + qa_b[1];
    }
}

// ---------------------------------------------------------------- launch

extern "C" void kernel_launch(void* const* d_in, const int* in_sizes, int n_in,
                              void* d_out, int out_size, void* d_ws, size_t ws_size,
                              hipStream_t stream) {
    const int*   input_ids = (const int*)d_in[0];
    const float* mems      = (const float*)d_in[1];
    const float* emb_table = (const float*)d_in[2];
    const float* qkv_w     = (const float*)d_in[3];
    const float* r_w       = (const float*)d_in[4];
    const float* o_w       = (const float*)d_in[5];
    const float* r_w_bias  = (const float*)d_in[6];
    const float* r_r_bias  = (const float*)d_in[7];
    const float* ln1_g     = (const float*)d_in[8];
    const float* ln1_b     = (const float*)d_in[9];
    const float* ff_w1     = (const float*)d_in[10];
    const float* ff_b1     = (const float*)d_in[11];
    const float* ff_w2     = (const float*)d_in[12];
    const float* ff_b2     = (const float*)d_in[13];
    const float* ln2_g     = (const float*)d_in[14];
    const float* ln2_b     = (const float*)d_in[15];
    const float* qa_w      = (const float*)d_in[16];
    const float* qa_b      = (const float*)d_in[17];

    float* out = (float*)d_out;
    float* out_mems = out + 2 * BSZ * QLEN;

    // workspace layout (bytes, 256-aligned)
    char* p = (char*)d_ws;
    auto nxt = [&](size_t bytes) { char* r = p; p += (bytes + 255) & ~(size_t)255; return r; };

    __bf16* pos_h  = (__bf16*)nxt((size_t)KLEN * 768 * 2);
    __bf16* pos_l  = (__bf16*)nxt((size_t)KLEN * 768 * 2);
    float*  core   = (float*) nxt((size_t)QLEN * BSZ * 768 * 4);
    __bf16* core_h = (__bf16*)nxt((size_t)QLEN * BSZ * 768 * 2);
    __bf16* core_l = (__bf16*)nxt((size_t)QLEN * BSZ * 768 * 2);
    // cat (split) region also reused as fp32 tmp (cat dead after qkv GEMM)
    char*   catreg = nxt((size_t)2 * KLEN * BSZ * 768 * 2);
    __bf16* cat_h  = (__bf16*)catreg;
    __bf16* cat_l  = cat_h + (size_t)KLEN * BSZ * 768;
    float*  tmp    = (float*)catreg;
    // w_heads region also reused as split ff_mid (w_heads dead after attention)
    char*   whreg  = nxt((size_t)KLEN * BSZ * 2304 * 4);
    float*  w_heads = (float*)whreg;
    __bf16* ffm_h  = (__bf16*)whreg;
    __bf16* ffm_l  = ffm_h + (size_t)QLEN * BSZ * D_INNER;
    float*  r_heads = (float*)nxt((size_t)KLEN * 768 * 4);
    __bf16* aout_h = (__bf16*)nxt((size_t)QLEN * BSZ * 768 * 2);
    __bf16* aout_l = (__bf16*)nxt((size_t)QLEN * BSZ * 768 * 2);
    // per-layer transposed split weights
    __bf16* qkvT_h = (__bf16*)nxt((size_t)2304 * 768 * 2);
    __bf16* qkvT_l = (__bf16*)nxt((size_t)2304 * 768 * 2);
    __bf16* rT_h   = (__bf16*)nxt((size_t)768 * 768 * 2);
    __bf16* rT_l   = (__bf16*)nxt((size_t)768 * 768 * 2);
    __bf16* oT_h   = (__bf16*)nxt((size_t)768 * 768 * 2);
    __bf16* oT_l   = (__bf16*)nxt((size_t)768 * 768 * 2);
    __bf16* f1T_h  = (__bf16*)nxt((size_t)3072 * 768 * 2);
    __bf16* f1T_l  = (__bf16*)nxt((size_t)3072 * 768 * 2);
    __bf16* f2T_h  = (__bf16*)nxt((size_t)768 * 3072 * 2);
    __bf16* f2T_l  = (__bf16*)nxt((size_t)768 * 3072 * 2);

    pos_emb_kernel<<<KLEN, 256, 0, stream>>>(pos_h, pos_l);
    embed_kernel<<<QLEN * BSZ, 256, 0, stream>>>(input_ids, emb_table, core);

    for (int l = 0; l < N_LAYER; l++) {
        wconvT_kernel<<<dim3(36, 12), 256, 0, stream>>>(qkv_w + (size_t)l * 768 * 2304, qkvT_h, qkvT_l, 768, 2304);
        wconvT_kernel<<<dim3(12, 12), 256, 0, stream>>>(r_w  + (size_t)l * 768 * 768,  rT_h,  rT_l,  768, 768);
        wconvT_kernel<<<dim3(12, 12), 256, 0, stream>>>(o_w  + (size_t)l * 768 * 768,  oT_h,  oT_l,  768, 768);
        wconvT_kernel<<<dim3(48, 12), 256, 0, stream>>>(ff_w1 + (size_t)l * 768 * 3072, f1T_h, f1T_l, 768, 3072);
        wconvT_kernel<<<dim3(12, 48), 256, 0, stream>>>(ff_w2 + (size_t)l * 3072 * 768, f2T_h, f2T_l, 3072, 768);

        prep_kernel<<<KLEN * BSZ, 256, 0, stream>>>(core, mems, cat_h, cat_l, out_mems, l);

        // qkv: [6144,768] @ [768,2304] -> fp32 w_heads
        mfma_gemm<0><<<dim3(18, 48), 256, 0, stream>>>(cat_h, cat_l, qkvT_h, qkvT_l,
            nullptr, nullptr, w_heads, nullptr, nullptr, 6144, 2304, 768);
        // position keys: [1536,768] @ [768,768] -> fp32 r_heads
        mfma_gemm<0><<<dim3(6, 12), 256, 0, stream>>>(pos_h, pos_l, rT_h, rT_l,
            nullptr, nullptr, r_heads, nullptr, nullptr, 1536, 768, 768);

        attn_flash_kernel<<<dim3(QLEN / 64, BSZ * N_HEAD), 256, 0, stream>>>(
            w_heads, r_heads, r_w_bias + (size_t)l * 768, r_r_bias + (size_t)l * 768,
            aout_h, aout_l);

        // out proj + residual -> fp32 tmp
        mfma_gemm<4><<<dim3(6, 32), 256, 0, stream>>>(aout_h, aout_l, oT_h, oT_l,
            nullptr, core, tmp, nullptr, nullptr, 4096, 768, 768);
        ln_kernel<1><<<4096, 256, 0, stream>>>(tmp, ln1_g + l * 768, ln1_b + l * 768,
                                               core, core_h, core_l);

        // ffn: bias+relu, split-bf16 output straight into ff2's A operand
        mfma_gemm<11><<<dim3(24, 32), 256, 0, stream>>>(core_h, core_l, f1T_h, f1T_l,
            ff_b1 + (size_t)l * D_INNER, nullptr, nullptr, ffm_h, ffm_l, 4096, D_INNER, 768);
        mfma_gemm<5><<<dim3(6, 32), 256, 0, stream>>>(ffm_h, ffm_l, f2T_h, f2T_l,
            ff_b2 + (size_t)l * 768, core, tmp, nullptr, nullptr, 4096, 768, D_INNER);
        ln_kernel<0><<<4096, 256, 0, stream>>>(tmp, ln2_g + l * 768, ln2_b + l * 768,
                                               core, nullptr, nullptr);
    }

    logits_kernel<<<QLEN * BSZ, 64, 0, stream>>>(core, qa_w, qa_b, out);
}